// Round 12
// baseline (654.014 us; speedup 1.0000x reference)
//
#include <hip/hip_runtime.h>
#include <hip/hip_bf16.h>

// MambaSSM B=1,T=1024,H=S=256,L=4 — f32 in, f32 OUT (round-11 discovery).
// Pipeline (verified V00): h=x@W_in^T+b_in; 4x{y=gelu(h@W1^T+b1)@W2^T+b2; h=LN(y)*g+b+h}
// dt=sigmoid(h@W_dt^T+b_dt); scan; u=vs@C^T+D*h; ou=u@W_out^T+b_out;
// out rows = [ou[0], repeat(ou[1:],256)] in FLOAT32.

#define T_SEQ 1024
#define H_DIM 256
#define TS 32

__device__ __forceinline__ float gelu_exact(float x) {
    return 0.5f * x * (1.0f + erff(x * 0.70710678118654752f));
}

// Y[M,N] = act( X[M,K] @ W[N,K]^T + bias ) (+ dscale[n]*dmat[m,n])
template<int ACT>
__global__ __launch_bounds__(256) void gemm_kernel(
    const float* __restrict__ X, const float* __restrict__ W,
    const float* __restrict__ bias, float* __restrict__ Y,
    int M, int N, int K,
    const float* __restrict__ dscale, const float* __restrict__ dmat)
{
    __shared__ float Xs[TS][TS + 1];
    __shared__ float Ws[TS][TS + 1];
    const int tid = threadIdx.x;
    const int tx = tid & 15;
    const int ty = tid >> 4;
    const int n0 = blockIdx.x * TS;
    const int m0 = blockIdx.y * TS;
    const int lr = tid >> 3;
    const int lc = (tid & 7) * 4;

    float acc[2][2] = {{0.f, 0.f}, {0.f, 0.f}};

    for (int k0 = 0; k0 < K; k0 += TS) {
        const float4 xv = *reinterpret_cast<const float4*>(&X[(size_t)(m0 + lr) * K + k0 + lc]);
        const float4 wv = *reinterpret_cast<const float4*>(&W[(size_t)(n0 + lr) * K + k0 + lc]);
        Xs[lr][lc + 0] = xv.x; Xs[lr][lc + 1] = xv.y; Xs[lr][lc + 2] = xv.z; Xs[lr][lc + 3] = xv.w;
        Ws[lr][lc + 0] = wv.x; Ws[lr][lc + 1] = wv.y; Ws[lr][lc + 2] = wv.z; Ws[lr][lc + 3] = wv.w;
        __syncthreads();
#pragma unroll
        for (int kk = 0; kk < TS; ++kk) {
            const float a0 = Xs[ty][kk],      a1 = Xs[ty + 16][kk];
            const float b0 = Ws[tx][kk],      b1 = Ws[tx + 16][kk];
            acc[0][0] = fmaf(a0, b0, acc[0][0]);
            acc[0][1] = fmaf(a0, b1, acc[0][1]);
            acc[1][0] = fmaf(a1, b0, acc[1][0]);
            acc[1][1] = fmaf(a1, b1, acc[1][1]);
        }
        __syncthreads();
    }

#pragma unroll
    for (int i = 0; i < 2; ++i)
#pragma unroll
        for (int j = 0; j < 2; ++j) {
            const int m_ = m0 + ty + 16 * i;
            const int n_ = n0 + tx + 16 * j;
            float r = acc[i][j];
            if (bias)   r += bias[n_];
            if (dscale) r += dscale[n_] * dmat[(size_t)m_ * N + n_];
            if (ACT == 1) r = gelu_exact(r);
            Y[(size_t)m_ * N + n_] = r;
        }
}

// h_out[row] = LN(y[row])*gamma+beta + h_in[row]
__global__ __launch_bounds__(256) void ln_residual_kernel(
    const float* __restrict__ Yin, const float* __restrict__ gamma,
    const float* __restrict__ beta, const float* __restrict__ hin,
    float* __restrict__ hout)
{
    __shared__ float red[8];
    const int row = blockIdx.x;
    const int c = threadIdx.x;
    const float y = Yin[(size_t)row * H_DIM + c];
    float s = y, s2 = y * y;
#pragma unroll
    for (int o = 1; o < 64; o <<= 1) {
        s  += __shfl_xor(s, o);
        s2 += __shfl_xor(s2, o);
    }
    const int wid = c >> 6;
    if ((c & 63) == 0) { red[wid] = s; red[4 + wid] = s2; }
    __syncthreads();
    const float ts  = red[0] + red[1] + red[2] + red[3];
    const float ts2 = red[4] + red[5] + red[6] + red[7];
    const float mean = ts * (1.0f / H_DIM);
    const float var  = ts2 * (1.0f / H_DIM) - mean * mean;
    const float inv  = rsqrtf(var + 1e-5f);
    hout[(size_t)row * H_DIM + c] =
        (y - mean) * inv * gamma[c] + beta[c] + hin[(size_t)row * H_DIM + c];
}

// vs[0]=h[0]; vs[t]=sigmoid(dtpre[t])*vs[t-1]+(1-sigmoid(dtpre[t]))*h[t]
__global__ __launch_bounds__(256) void scan_kernel(
    const float* __restrict__ dtpre, const float* __restrict__ h,
    float* __restrict__ vs)
{
    const int c = threadIdx.x;
    float v = h[c];
    vs[c] = v;
    for (int t = 1; t < T_SEQ; ++t) {
        const float dp = dtpre[(size_t)t * H_DIM + c];
        const float hv = h[(size_t)t * H_DIM + c];
        const float dt = 1.0f / (1.0f + expf(-dp));
        v = dt * v + (1.0f - dt) * hv;
        vs[(size_t)t * H_DIM + c] = v;
    }
}

// out rows (f32): row0 = src[0] once; i>=1: 256 copies of src[i] at 1+(i-1)*256.
// Grid (1024, 4): x = source row, y = quarter of the copies.
__global__ __launch_bounds__(256) void replicate_f32(
    const float* __restrict__ src, float* __restrict__ out)
{
    const int i = blockIdx.x;
    const int tid = threadIdx.x;
    const int cg = tid & 63;     // col group: 4 floats each
    const int sub = tid >> 6;    // 0..3

    const float4 v = *reinterpret_cast<const float4*>(&src[(size_t)i * H_DIM + cg * 4]);

    if (i == 0) {
        if (blockIdx.y == 0 && sub == 0)
            *reinterpret_cast<float4*>(&out[(size_t)cg * 4]) = v;
    } else {
        const size_t base = (size_t)(1 + (i - 1) * H_DIM + blockIdx.y * 64) * H_DIM;
#pragma unroll 4
        for (int it = 0; it < 16; ++it) {
            const size_t row_off = base + (size_t)(sub + it * 4) * H_DIM;
            *reinterpret_cast<float4*>(&out[row_off + cg * 4]) = v;
        }
    }
}

extern "C" void kernel_launch(void* const* d_in, const int* in_sizes, int n_in,
                              void* d_out, int out_size, void* d_ws, size_t ws_size,
                              hipStream_t stream)
{
    const float* x     = (const float*)d_in[0];
    const float* W_in  = (const float*)d_in[1];
    const float* b_in  = (const float*)d_in[2];
    const float* W1    = (const float*)d_in[3];
    const float* b1    = (const float*)d_in[4];
    const float* W2    = (const float*)d_in[5];
    const float* b2    = (const float*)d_in[6];
    const float* gamma = (const float*)d_in[7];
    const float* beta  = (const float*)d_in[8];
    const float* W_dt  = (const float*)d_in[9];
    const float* b_dt  = (const float*)d_in[10];
    const float* C     = (const float*)d_in[11];
    const float* D     = (const float*)d_in[12];
    const float* W_out = (const float*)d_in[13];
    const float* b_out = (const float*)d_in[14];
    float* out = (float*)d_out;   // f32 output (round-11 discovery)

    // 4 MB aliased workspace (device-verified in rounds 2-5).
    float* ws    = (float*)d_ws;
    float* h     = ws;
    float* y1    = ws + 262144;
    float* y2    = ws + 786432;
    float* dtpre = ws + 262144;   // alias y1.lo (y1 dead after MLP loop)
    float* u     = ws + 524288;   // alias y1.hi
    float* vs    = ws + 786432;   // alias y2 (dead after MLP loop)
    float* ou    = ws + 786432;   // alias vs (dead after u-gemm)

    const dim3 blk(256);

    gemm_kernel<0><<<dim3(H_DIM / TS, T_SEQ / TS), blk, 0, stream>>>(
        x, W_in, b_in, h, T_SEQ, H_DIM, H_DIM, nullptr, nullptr);

    for (int l = 0; l < 4; ++l) {
        gemm_kernel<1><<<dim3(512 / TS, T_SEQ / TS), blk, 0, stream>>>(
            h, W1 + (size_t)l * 512 * 256, b1 + l * 512, y1,
            T_SEQ, 512, 256, nullptr, nullptr);
        gemm_kernel<0><<<dim3(H_DIM / TS, T_SEQ / TS), blk, 0, stream>>>(
            y1, W2 + (size_t)l * 256 * 512, b2 + l * 256, y2,
            T_SEQ, H_DIM, 512, nullptr, nullptr);
        ln_residual_kernel<<<dim3(T_SEQ), blk, 0, stream>>>(
            y2, gamma + l * 256, beta + l * 256, h, h);
    }

    gemm_kernel<0><<<dim3(H_DIM / TS, T_SEQ / TS), blk, 0, stream>>>(
        h, W_dt, b_dt, dtpre, T_SEQ, H_DIM, H_DIM, nullptr, nullptr);

    scan_kernel<<<dim3(1), blk, 0, stream>>>(dtpre, h, vs);

    gemm_kernel<0><<<dim3(H_DIM / TS, T_SEQ / TS), blk, 0, stream>>>(
        vs, C, nullptr, u, T_SEQ, H_DIM, H_DIM, D, h);

    gemm_kernel<0><<<dim3(H_DIM / TS, T_SEQ / TS), blk, 0, stream>>>(
        u, W_out, b_out, ou, T_SEQ, H_DIM, H_DIM, nullptr, nullptr);

    replicate_f32<<<dim3(T_SEQ, 4), blk, 0, stream>>>(ou, out);
}

// Round 13
// 526.760 us; speedup vs baseline: 1.2416x; 1.2416x over previous
//
#include <hip/hip_runtime.h>
#include <hip/hip_bf16.h>

// MambaSSM B=1,T=1024,H=S=256,L=4 — f32 in/out. Round 13: parallel scan +
// float4-LDS GEMM inner loop. Pipeline verified (V00, rounds 2-12).

#define T_SEQ 1024
#define H_DIM 256
#define TS 32

__device__ __forceinline__ float gelu_exact(float x) {
    return 0.5f * x * (1.0f + erff(x * 0.70710678118654752f));
}

// Y[M,N] = act( X[M,K] @ W[N,K]^T + bias ) (+ dscale[n]*dmat[m,n])
template<int ACT>
__global__ __launch_bounds__(256) void gemm_kernel(
    const float* __restrict__ X, const float* __restrict__ W,
    const float* __restrict__ bias, float* __restrict__ Y,
    int M, int N, int K,
    const float* __restrict__ dscale, const float* __restrict__ dmat)
{
    __shared__ float Xs[TS][TS + 4];   // stride 36 f32 = 144B, 16B-aligned rows
    __shared__ float Ws[TS][TS + 4];
    const int tid = threadIdx.x;
    const int tx = tid & 15;
    const int ty = tid >> 4;
    const int n0 = blockIdx.x * TS;
    const int m0 = blockIdx.y * TS;
    const int lr = tid >> 3;
    const int lc = (tid & 7) * 4;

    float acc[2][2] = {{0.f, 0.f}, {0.f, 0.f}};

    for (int k0 = 0; k0 < K; k0 += TS) {
        const float4 xv = *reinterpret_cast<const float4*>(&X[(size_t)(m0 + lr) * K + k0 + lc]);
        const float4 wv = *reinterpret_cast<const float4*>(&W[(size_t)(n0 + lr) * K + k0 + lc]);
        *reinterpret_cast<float4*>(&Xs[lr][lc]) = xv;
        *reinterpret_cast<float4*>(&Ws[lr][lc]) = wv;
        __syncthreads();
#pragma unroll
        for (int kk = 0; kk < TS; kk += 4) {
            const float4 a0 = *reinterpret_cast<const float4*>(&Xs[ty][kk]);
            const float4 a1 = *reinterpret_cast<const float4*>(&Xs[ty + 16][kk]);
            const float4 b0 = *reinterpret_cast<const float4*>(&Ws[tx][kk]);
            const float4 b1 = *reinterpret_cast<const float4*>(&Ws[tx + 16][kk]);
            acc[0][0] = fmaf(a0.w, b0.w, fmaf(a0.z, b0.z, fmaf(a0.y, b0.y, fmaf(a0.x, b0.x, acc[0][0]))));
            acc[0][1] = fmaf(a0.w, b1.w, fmaf(a0.z, b1.z, fmaf(a0.y, b1.y, fmaf(a0.x, b1.x, acc[0][1]))));
            acc[1][0] = fmaf(a1.w, b0.w, fmaf(a1.z, b0.z, fmaf(a1.y, b0.y, fmaf(a1.x, b0.x, acc[1][0]))));
            acc[1][1] = fmaf(a1.w, b1.w, fmaf(a1.z, b1.z, fmaf(a1.y, b1.y, fmaf(a1.x, b1.x, acc[1][1]))));
        }
        __syncthreads();
    }

#pragma unroll
    for (int i = 0; i < 2; ++i)
#pragma unroll
        for (int j = 0; j < 2; ++j) {
            const int m_ = m0 + ty + 16 * i;
            const int n_ = n0 + tx + 16 * j;
            float r = acc[i][j];
            if (bias)   r += bias[n_];
            if (dscale) r += dscale[n_] * dmat[(size_t)m_ * N + n_];
            if (ACT == 1) r = gelu_exact(r);
            Y[(size_t)m_ * N + n_] = r;
        }
}

// h_out[row] = LN(y[row])*gamma+beta + h_in[row]
__global__ __launch_bounds__(256) void ln_residual_kernel(
    const float* __restrict__ Yin, const float* __restrict__ gamma,
    const float* __restrict__ beta, const float* __restrict__ hin,
    float* __restrict__ hout)
{
    __shared__ float red[8];
    const int row = blockIdx.x;
    const int c = threadIdx.x;
    const float y = Yin[(size_t)row * H_DIM + c];
    float s = y, s2 = y * y;
#pragma unroll
    for (int o = 1; o < 64; o <<= 1) {
        s  += __shfl_xor(s, o);
        s2 += __shfl_xor(s2, o);
    }
    const int wid = c >> 6;
    if ((c & 63) == 0) { red[wid] = s; red[4 + wid] = s2; }
    __syncthreads();
    const float ts  = red[0] + red[1] + red[2] + red[3];
    const float ts2 = red[4] + red[5] + red[6] + red[7];
    const float mean = ts * (1.0f / H_DIM);
    const float var  = ts2 * (1.0f / H_DIM) - mean * mean;
    const float inv  = rsqrtf(var + 1e-5f);
    hout[(size_t)row * H_DIM + c] =
        (y - mean) * inv * gamma[c] + beta[c] + hin[(size_t)row * H_DIM + c];
}

// Parallel scan: v_t = a_t*v_{t-1} + b_t with a_0=0, b_0=h_0 (uniform).
// Affine compose: new∘old = (a*A, a*B+b). Block = 64 channels x 16 chunks
// (1024 threads); each thread scans 64 consecutive t; coalesced loads
// (lanes = adjacent channels). Grid = 4 blocks.
__global__ __launch_bounds__(1024) void scan_par(
    const float* __restrict__ dtpre, const float* __restrict__ h,
    float* __restrict__ vs)
{
    __shared__ float sA[16][64], sB[16][64];
    const int chl   = threadIdx.x & 63;
    const int chunk = threadIdx.x >> 6;         // 0..15
    const int c  = blockIdx.x * 64 + chl;
    const int t0 = chunk * 64;

    // pass 1: chunk-local affine composition
    float A = 1.f, B = 0.f;
    for (int i = 0; i < 64; ++i) {
        const int t = t0 + i;
        const float hv = h[(size_t)t * H_DIM + c];
        float a, b;
        if (t == 0) { a = 0.f; b = hv; }
        else {
            const float dt = 1.0f / (1.0f + __expf(-dtpre[(size_t)t * H_DIM + c]));
            a = dt; b = (1.0f - dt) * hv;
        }
        A = a * A;
        B = fmaf(a, B, b);
    }
    sA[chunk][chl] = A; sB[chunk][chl] = B;
    __syncthreads();

    // exclusive prefix over 16 chunks, serial per channel (chunk-0 threads)
    if (chunk == 0) {
        float pA = 1.f, pB = 0.f;
        for (int j = 0; j < 16; ++j) {
            const float cA = sA[j][chl], cB = sB[j][chl];
            sA[j][chl] = pA; sB[j][chl] = pB;
            pA = cA * pA;
            pB = fmaf(cA, pB, cB);
        }
    }
    __syncthreads();

    // pass 2: apply prefix, recompute a,b, write vs
    A = sA[chunk][chl]; B = sB[chunk][chl];
    for (int i = 0; i < 64; ++i) {
        const int t = t0 + i;
        const float hv = h[(size_t)t * H_DIM + c];
        float a, b;
        if (t == 0) { a = 0.f; b = hv; }
        else {
            const float dt = 1.0f / (1.0f + __expf(-dtpre[(size_t)t * H_DIM + c]));
            a = dt; b = (1.0f - dt) * hv;
        }
        A = a * A;
        B = fmaf(a, B, b);
        vs[(size_t)t * H_DIM + c] = B;
    }
}

// out rows (f32): row0 = src[0] once; i>=1: 256 copies of src[i] at 1+(i-1)*256.
__global__ __launch_bounds__(256) void replicate_f32(
    const float* __restrict__ src, float* __restrict__ out)
{
    const int i = blockIdx.x;
    const int tid = threadIdx.x;
    const int cg = tid & 63;
    const int sub = tid >> 6;

    const float4 v = *reinterpret_cast<const float4*>(&src[(size_t)i * H_DIM + cg * 4]);

    if (i == 0) {
        if (blockIdx.y == 0 && sub == 0)
            *reinterpret_cast<float4*>(&out[(size_t)cg * 4]) = v;
    } else {
        const size_t base = (size_t)(1 + (i - 1) * H_DIM + blockIdx.y * 64) * H_DIM;
#pragma unroll 4
        for (int it = 0; it < 16; ++it) {
            const size_t row_off = base + (size_t)(sub + it * 4) * H_DIM;
            *reinterpret_cast<float4*>(&out[row_off + cg * 4]) = v;
        }
    }
}

extern "C" void kernel_launch(void* const* d_in, const int* in_sizes, int n_in,
                              void* d_out, int out_size, void* d_ws, size_t ws_size,
                              hipStream_t stream)
{
    const float* x     = (const float*)d_in[0];
    const float* W_in  = (const float*)d_in[1];
    const float* b_in  = (const float*)d_in[2];
    const float* W1    = (const float*)d_in[3];
    const float* b1    = (const float*)d_in[4];
    const float* W2    = (const float*)d_in[5];
    const float* b2    = (const float*)d_in[6];
    const float* gamma = (const float*)d_in[7];
    const float* beta  = (const float*)d_in[8];
    const float* W_dt  = (const float*)d_in[9];
    const float* b_dt  = (const float*)d_in[10];
    const float* C     = (const float*)d_in[11];
    const float* D     = (const float*)d_in[12];
    const float* W_out = (const float*)d_in[13];
    const float* b_out = (const float*)d_in[14];
    float* out = (float*)d_out;

    float* ws    = (float*)d_ws;
    float* h     = ws;
    float* y1    = ws + 262144;
    float* y2    = ws + 786432;
    float* dtpre = ws + 262144;   // alias y1.lo (y1 dead after MLP loop)
    float* u     = ws + 524288;   // alias y1.hi
    float* vs    = ws + 786432;   // alias y2 (dead after MLP loop)
    float* ou    = ws + 786432;   // alias vs (dead after u-gemm)

    const dim3 blk(256);

    gemm_kernel<0><<<dim3(H_DIM / TS, T_SEQ / TS), blk, 0, stream>>>(
        x, W_in, b_in, h, T_SEQ, H_DIM, H_DIM, nullptr, nullptr);

    for (int l = 0; l < 4; ++l) {
        gemm_kernel<1><<<dim3(512 / TS, T_SEQ / TS), blk, 0, stream>>>(
            h, W1 + (size_t)l * 512 * 256, b1 + l * 512, y1,
            T_SEQ, 512, 256, nullptr, nullptr);
        gemm_kernel<0><<<dim3(H_DIM / TS, T_SEQ / TS), blk, 0, stream>>>(
            y1, W2 + (size_t)l * 256 * 512, b2 + l * 256, y2,
            T_SEQ, H_DIM, 512, nullptr, nullptr);
        ln_residual_kernel<<<dim3(T_SEQ), blk, 0, stream>>>(
            y2, gamma + l * 256, beta + l * 256, h, h);
    }

    gemm_kernel<0><<<dim3(H_DIM / TS, T_SEQ / TS), blk, 0, stream>>>(
        h, W_dt, b_dt, dtpre, T_SEQ, H_DIM, H_DIM, nullptr, nullptr);

    scan_par<<<dim3(H_DIM / 64), dim3(1024), 0, stream>>>(dtpre, h, vs);

    gemm_kernel<0><<<dim3(H_DIM / TS, T_SEQ / TS), blk, 0, stream>>>(
        vs, C, nullptr, u, T_SEQ, H_DIM, H_DIM, D, h);

    gemm_kernel<0><<<dim3(H_DIM / TS, T_SEQ / TS), blk, 0, stream>>>(
        u, W_out, b_out, ou, T_SEQ, H_DIM, H_DIM, nullptr, nullptr);

    replicate_f32<<<dim3(T_SEQ, 4), blk, 0, stream>>>(ou, out);
}

// Round 15
// 471.857 us; speedup vs baseline: 1.3860x; 1.1164x over previous
//
#include <hip/hip_runtime.h>
#include <hip/hip_bf16.h>

// MambaSSM B=1,T=1024,H=S=256,L=4 — f32 in/out.
// Round 15: MFMA split-bf16 GEMM stack (round-14 fix: native ext_vector acc).
// Scan (parallel affine), LN, replicate unchanged (verified rounds 12-13).

#define T_SEQ 1024
#define H_DIM 256

typedef __attribute__((ext_vector_type(8))) short short8;
typedef __attribute__((ext_vector_type(4))) float f32x4;

__device__ __forceinline__ float gelu_exact(float x) {
    return 0.5f * x * (1.0f + erff(x * 0.70710678118654752f));
}

__device__ __forceinline__ void split_bf16(float x, unsigned short& h, unsigned short& l) {
    __hip_bfloat16 bh = __float2bfloat16(x);          // RN
    float fh = __bfloat162float(bh);
    __hip_bfloat16 bl = __float2bfloat16(x - fh);
    __builtin_memcpy(&h, &bh, 2);
    __builtin_memcpy(&l, &bl, 2);
}

// Y[M,N] = act( X[M,K] @ W[N,K]^T + bias ) (+ dscale[n]*dmat[m,n])
// Tile 32x32/block, 256 threads = 4 waves; wave (wr,wc) computes one 16x16
// sub-tile via mfma_f32_16x16x32_bf16, split-bf16 3-term for f32 precision.
// A/B frag: lane l reads [16*w? + (l&15)][8*(l>>4)..+8] — shared k-mapping
// makes the dot invariant to k-permutation. D: col=l&15, row=4*(l>>4)+j (m89).
template<int ACT>
__global__ __launch_bounds__(256) void gemm_mfma(
    const float* __restrict__ X, const float* __restrict__ W,
    const float* __restrict__ bias, float* __restrict__ Y,
    int M, int N, int K,
    const float* __restrict__ dscale, const float* __restrict__ dmat)
{
    // 80B row stride: b128 frag reads 16B-aligned, ~2-way banks (free)
    __shared__ unsigned short Xh[32][40], Xl[32][40], Wh[32][40], Wl[32][40];

    const int tid  = threadIdx.x;
    const int lr   = tid >> 3;          // stage row 0..31
    const int lc   = (tid & 7) * 4;     // stage col 0,4..28
    const int wave = tid >> 6;          // 0..3
    const int lane = tid & 63;
    const int wr   = wave >> 1, wc = wave & 1;
    const int l15  = lane & 15, ko = lane >> 4;
    const int n0   = blockIdx.x * 32;
    const int m0   = blockIdx.y * 32;

    f32x4 acc = {0.f, 0.f, 0.f, 0.f};

    for (int k0 = 0; k0 < K; k0 += 32) {
        const float4 xv = *reinterpret_cast<const float4*>(&X[(size_t)(m0 + lr) * K + k0 + lc]);
        const float4 wv = *reinterpret_cast<const float4*>(&W[(size_t)(n0 + lr) * K + k0 + lc]);
        ushort4 xh, xl, wh, wl;
        split_bf16(xv.x, xh.x, xl.x); split_bf16(xv.y, xh.y, xl.y);
        split_bf16(xv.z, xh.z, xl.z); split_bf16(xv.w, xh.w, xl.w);
        split_bf16(wv.x, wh.x, wl.x); split_bf16(wv.y, wh.y, wl.y);
        split_bf16(wv.z, wh.z, wl.z); split_bf16(wv.w, wh.w, wl.w);
        *reinterpret_cast<ushort4*>(&Xh[lr][lc]) = xh;
        *reinterpret_cast<ushort4*>(&Xl[lr][lc]) = xl;
        *reinterpret_cast<ushort4*>(&Wh[lr][lc]) = wh;
        *reinterpret_cast<ushort4*>(&Wl[lr][lc]) = wl;
        __syncthreads();

        const short8 ah = *reinterpret_cast<const short8*>(&Xh[16 * wr + l15][8 * ko]);
        const short8 al = *reinterpret_cast<const short8*>(&Xl[16 * wr + l15][8 * ko]);
        const short8 bh = *reinterpret_cast<const short8*>(&Wh[16 * wc + l15][8 * ko]);
        const short8 bl = *reinterpret_cast<const short8*>(&Wl[16 * wc + l15][8 * ko]);
        acc = __builtin_amdgcn_mfma_f32_16x16x32_bf16(ah, bh, acc, 0, 0, 0);
        acc = __builtin_amdgcn_mfma_f32_16x16x32_bf16(ah, bl, acc, 0, 0, 0);
        acc = __builtin_amdgcn_mfma_f32_16x16x32_bf16(al, bh, acc, 0, 0, 0);
        __syncthreads();
    }

    const int n_ = n0 + 16 * wc + l15;
#pragma unroll
    for (int j = 0; j < 4; ++j) {
        const int m_ = m0 + 16 * wr + 4 * ko + j;
        float r = acc[j];
        if (bias)   r += bias[n_];
        if (dscale) r += dscale[n_] * dmat[(size_t)m_ * N + n_];
        if (ACT == 1) r = gelu_exact(r);
        Y[(size_t)m_ * N + n_] = r;
    }
}

// h_out[row] = LN(y[row])*gamma+beta + h_in[row]
__global__ __launch_bounds__(256) void ln_residual_kernel(
    const float* __restrict__ Yin, const float* __restrict__ gamma,
    const float* __restrict__ beta, const float* __restrict__ hin,
    float* __restrict__ hout)
{
    __shared__ float red[8];
    const int row = blockIdx.x;
    const int c = threadIdx.x;
    const float y = Yin[(size_t)row * H_DIM + c];
    float s = y, s2 = y * y;
#pragma unroll
    for (int o = 1; o < 64; o <<= 1) {
        s  += __shfl_xor(s, o);
        s2 += __shfl_xor(s2, o);
    }
    const int wid = c >> 6;
    if ((c & 63) == 0) { red[wid] = s; red[4 + wid] = s2; }
    __syncthreads();
    const float ts  = red[0] + red[1] + red[2] + red[3];
    const float ts2 = red[4] + red[5] + red[6] + red[7];
    const float mean = ts * (1.0f / H_DIM);
    const float var  = ts2 * (1.0f / H_DIM) - mean * mean;
    const float inv  = rsqrtf(var + 1e-5f);
    hout[(size_t)row * H_DIM + c] =
        (y - mean) * inv * gamma[c] + beta[c] + hin[(size_t)row * H_DIM + c];
}

// Parallel scan: v_t = a_t*v_{t-1} + b_t, a_0=0, b_0=h_0. 4 blocks x 1024 thr.
__global__ __launch_bounds__(1024) void scan_par(
    const float* __restrict__ dtpre, const float* __restrict__ h,
    float* __restrict__ vs)
{
    __shared__ float sA[16][64], sB[16][64];
    const int chl   = threadIdx.x & 63;
    const int chunk = threadIdx.x >> 6;
    const int c  = blockIdx.x * 64 + chl;
    const int t0 = chunk * 64;

    float A = 1.f, B = 0.f;
    for (int i = 0; i < 64; ++i) {
        const int t = t0 + i;
        const float hv = h[(size_t)t * H_DIM + c];
        float a, b;
        if (t == 0) { a = 0.f; b = hv; }
        else {
            const float dt = 1.0f / (1.0f + __expf(-dtpre[(size_t)t * H_DIM + c]));
            a = dt; b = (1.0f - dt) * hv;
        }
        A = a * A;
        B = fmaf(a, B, b);
    }
    sA[chunk][chl] = A; sB[chunk][chl] = B;
    __syncthreads();

    if (chunk == 0) {
        float pA = 1.f, pB = 0.f;
        for (int j = 0; j < 16; ++j) {
            const float cA = sA[j][chl], cB = sB[j][chl];
            sA[j][chl] = pA; sB[j][chl] = pB;
            pA = cA * pA;
            pB = fmaf(cA, pB, cB);
        }
    }
    __syncthreads();

    A = sA[chunk][chl]; B = sB[chunk][chl];
    for (int i = 0; i < 64; ++i) {
        const int t = t0 + i;
        const float hv = h[(size_t)t * H_DIM + c];
        float a, b;
        if (t == 0) { a = 0.f; b = hv; }
        else {
            const float dt = 1.0f / (1.0f + __expf(-dtpre[(size_t)t * H_DIM + c]));
            a = dt; b = (1.0f - dt) * hv;
        }
        A = a * A;
        B = fmaf(a, B, b);
        vs[(size_t)t * H_DIM + c] = B;
    }
}

// out rows (f32): row0 = src[0] once; i>=1: 256 copies of src[i] at 1+(i-1)*256.
__global__ __launch_bounds__(256) void replicate_f32(
    const float* __restrict__ src, float* __restrict__ out)
{
    const int i = blockIdx.x;
    const int tid = threadIdx.x;
    const int cg = tid & 63;
    const int sub = tid >> 6;

    const float4 v = *reinterpret_cast<const float4*>(&src[(size_t)i * H_DIM + cg * 4]);

    if (i == 0) {
        if (blockIdx.y == 0 && sub == 0)
            *reinterpret_cast<float4*>(&out[(size_t)cg * 4]) = v;
    } else {
        const size_t base = (size_t)(1 + (i - 1) * H_DIM + blockIdx.y * 64) * H_DIM;
#pragma unroll 4
        for (int it = 0; it < 16; ++it) {
            const size_t row_off = base + (size_t)(sub + it * 4) * H_DIM;
            *reinterpret_cast<float4*>(&out[row_off + cg * 4]) = v;
        }
    }
}

extern "C" void kernel_launch(void* const* d_in, const int* in_sizes, int n_in,
                              void* d_out, int out_size, void* d_ws, size_t ws_size,
                              hipStream_t stream)
{
    const float* x     = (const float*)d_in[0];
    const float* W_in  = (const float*)d_in[1];
    const float* b_in  = (const float*)d_in[2];
    const float* W1    = (const float*)d_in[3];
    const float* b1    = (const float*)d_in[4];
    const float* W2    = (const float*)d_in[5];
    const float* b2    = (const float*)d_in[6];
    const float* gamma = (const float*)d_in[7];
    const float* beta  = (const float*)d_in[8];
    const float* W_dt  = (const float*)d_in[9];
    const float* b_dt  = (const float*)d_in[10];
    const float* C     = (const float*)d_in[11];
    const float* D     = (const float*)d_in[12];
    const float* W_out = (const float*)d_in[13];
    const float* b_out = (const float*)d_in[14];
    float* out = (float*)d_out;

    float* ws    = (float*)d_ws;
    float* h     = ws;
    float* y1    = ws + 262144;
    float* y2    = ws + 786432;
    float* dtpre = ws + 262144;   // alias y1.lo (y1 dead after MLP loop)
    float* u     = ws + 524288;   // alias y1.hi
    float* vs    = ws + 786432;   // alias y2 (dead after MLP loop)
    float* ou    = ws + 786432;   // alias vs (dead after u-gemm)

    const dim3 blk(256);

    gemm_mfma<0><<<dim3(H_DIM / 32, T_SEQ / 32), blk, 0, stream>>>(
        x, W_in, b_in, h, T_SEQ, H_DIM, H_DIM, nullptr, nullptr);

    for (int l = 0; l < 4; ++l) {
        gemm_mfma<1><<<dim3(512 / 32, T_SEQ / 32), blk, 0, stream>>>(
            h, W1 + (size_t)l * 512 * 256, b1 + l * 512, y1,
            T_SEQ, 512, 256, nullptr, nullptr);
        gemm_mfma<0><<<dim3(H_DIM / 32, T_SEQ / 32), blk, 0, stream>>>(
            y1, W2 + (size_t)l * 256 * 512, b2 + l * 256, y2,
            T_SEQ, H_DIM, 512, nullptr, nullptr);
        ln_residual_kernel<<<dim3(T_SEQ), blk, 0, stream>>>(
            y2, gamma + l * 256, beta + l * 256, h, h);
    }

    gemm_mfma<0><<<dim3(H_DIM / 32, T_SEQ / 32), blk, 0, stream>>>(
        h, W_dt, b_dt, dtpre, T_SEQ, H_DIM, H_DIM, nullptr, nullptr);

    scan_par<<<dim3(H_DIM / 64), dim3(1024), 0, stream>>>(dtpre, h, vs);

    gemm_mfma<0><<<dim3(H_DIM / 32, T_SEQ / 32), blk, 0, stream>>>(
        vs, C, nullptr, u, T_SEQ, H_DIM, H_DIM, D, h);

    gemm_mfma<0><<<dim3(H_DIM / 32, T_SEQ / 32), blk, 0, stream>>>(
        u, W_out, b_out, ou, T_SEQ, H_DIM, H_DIM, nullptr, nullptr);

    replicate_f32<<<dim3(T_SEQ, 4), blk, 0, stream>>>(ou, out);
}